// Round 1
// baseline (388.855 us; speedup 1.0000x reference)
//
#include <hip/hip_runtime.h>
#include <math.h>

#define NB 16
#define NE 5
#define LL 128
#define HH 768
#define NK 21
#define NCLS 3
#define NN (NB*NE)   // 80

// ---------------- K1: inverse L2 norms of each (n,q) row ----------------
__global__ __launch_bounds__(256) void k_invnorm(const float* __restrict__ hid,
                                                 float* __restrict__ invn) {
    int row = blockIdx.x;                    // 0..NN*LL-1
    const float* x = hid + (size_t)row * HH;
    float ss = 0.f;
    for (int h = threadIdx.x; h < HH; h += 256) { float v = x[h]; ss += v * v; }
    __shared__ float red[4];
    int lane = threadIdx.x & 63, w = threadIdx.x >> 6;
    #pragma unroll
    for (int o = 32; o > 0; o >>= 1) ss += __shfl_down(ss, o, 64);
    if (lane == 0) red[w] = ss;
    __syncthreads();
    if (threadIdx.x == 0) {
        float t = red[0] + red[1] + red[2] + red[3];
        invn[row] = 1.0f / fmaxf(sqrtf(t), 1e-12f);
    }
}

// ---------------- K2: sim tile + kernel pooling ----------------
// grid: (qh=2, pair=25, b=16). Each block: 64 q rows x 128 d cols for pair (e, e').
__global__ __launch_bounds__(256) void k_simpool(
    const float* __restrict__ hid, const float* __restrict__ invn,
    const float* __restrict__ mask_text, const float* __restrict__ mask_evidence,
    float* __restrict__ kp_att, float* __restrict__ kp_sel)
{
    const int qh = blockIdx.x;          // 0..1
    const int pair = blockIdx.y;        // 0..24
    const int b = blockIdx.z;           // 0..15
    const int e = pair / NE, ep = pair % NE;
    const int nq = b * NE + e;          // query doc
    const int nd = b * NE + ep;         // key doc

    const int tid = threadIdx.x;
    const int tx = tid & 15, ty = tid >> 4;

    __shared__ float As[64][33];
    __shared__ float Bs[128][33];

    const float* Ag = hid + ((size_t)nq * LL + qh * 64) * HH;
    const float* Bg = hid + (size_t)nd * LL * HH;

    float acc[4][8];
    #pragma unroll
    for (int i = 0; i < 4; ++i)
        #pragma unroll
        for (int j = 0; j < 8; ++j) acc[i][j] = 0.f;

    for (int h0 = 0; h0 < HH; h0 += 32) {
        #pragma unroll
        for (int r = 0; r < 2; ++r) {
            int idx = tid + r * 256;
            int row = idx >> 3, c4 = (idx & 7) * 4;
            const float4 v = *reinterpret_cast<const float4*>(Ag + (size_t)row * HH + h0 + c4);
            As[row][c4 + 0] = v.x; As[row][c4 + 1] = v.y;
            As[row][c4 + 2] = v.z; As[row][c4 + 3] = v.w;
        }
        #pragma unroll
        for (int r = 0; r < 4; ++r) {
            int idx = tid + r * 256;
            int row = idx >> 3, c4 = (idx & 7) * 4;
            const float4 v = *reinterpret_cast<const float4*>(Bg + (size_t)row * HH + h0 + c4);
            Bs[row][c4 + 0] = v.x; Bs[row][c4 + 1] = v.y;
            Bs[row][c4 + 2] = v.z; Bs[row][c4 + 3] = v.w;
        }
        __syncthreads();
        #pragma unroll
        for (int kk = 0; kk < 32; ++kk) {
            float a[4], bb[8];
            #pragma unroll
            for (int i = 0; i < 4; ++i) a[i] = As[ty * 4 + i][kk];
            #pragma unroll
            for (int j = 0; j < 8; ++j) bb[j] = Bs[j * 16 + tx][kk];
            #pragma unroll
            for (int i = 0; i < 4; ++i)
                #pragma unroll
                for (int j = 0; j < 8; ++j) acc[i][j] += a[i] * bb[j];
        }
        __syncthreads();
    }

    // scale by inverse norms (l2norm is a row scaling)
    float iq[4], idv[8];
    #pragma unroll
    for (int i = 0; i < 4; ++i) iq[i] = invn[nq * LL + qh * 64 + ty * 4 + i];
    #pragma unroll
    for (int j = 0; j < 8; ++j) idv[j] = invn[nd * LL + j * 16 + tx];
    #pragma unroll
    for (int i = 0; i < 4; ++i)
        #pragma unroll
        for (int j = 0; j < 8; ++j) acc[i][j] *= iq[i] * idv[j];

    const bool diag = (e == ep);
    float mt[8], me[8];
    #pragma unroll
    for (int j = 0; j < 8; ++j) {
        mt[j] = mask_text[nd * LL + j * 16 + tx];
        me[j] = diag ? mask_evidence[nd * LL + j * 16 + tx] : 0.f;
    }

    for (int k = 0; k < NK; ++k) {
        const float mu = (k == 0) ? 1.0f : (0.95f - 0.1f * (k - 1));
        const float cc = (k == 0) ? 5.0e5f : 50.0f;
        float pa[4] = {0.f, 0.f, 0.f, 0.f};
        float ps[4] = {0.f, 0.f, 0.f, 0.f};
        #pragma unroll
        for (int i = 0; i < 4; ++i) {
            #pragma unroll
            for (int j = 0; j < 8; ++j) {
                float d = acc[i][j] - mu;
                float g = __expf(-cc * d * d);
                pa[i] += mt[j] * g;
                ps[i] += me[j] * g;
            }
        }
        // reduce over tx (16-lane groups)
        #pragma unroll
        for (int o = 1; o < 16; o <<= 1) {
            #pragma unroll
            for (int i = 0; i < 4; ++i) pa[i] += __shfl_xor(pa[i], o, 64);
        }
        if (diag) {
            #pragma unroll
            for (int o = 1; o < 16; o <<= 1) {
                #pragma unroll
                for (int i = 0; i < 4; ++i) ps[i] += __shfl_xor(ps[i], o, 64);
            }
        }
        if (tx == 0) {
            #pragma unroll
            for (int i = 0; i < 4; ++i) {
                int q = qh * 64 + ty * 4 + i;
                kp_att[(((size_t)ep * NN + nq) * LL + q) * NK + k] = pa[i];
                if (diag) kp_sel[((size_t)nq * LL + q) * NK + k] = ps[i];
            }
        }
    }
}

// ---------------- K3: sel logits per doc ----------------
__global__ __launch_bounds__(128) void k_sel(
    const float* __restrict__ kp_sel, const float* __restrict__ mask_claim,
    const float* __restrict__ W_sel, const float* __restrict__ b_sel,
    float* __restrict__ dsel)
{
    int n = blockIdx.x;        // 0..79
    int q = threadIdx.x;       // 0..127
    __shared__ float s_lp[NK][LL + 1];
    __shared__ float s_w[LL];
    float w = mask_claim[n * LL + q];
    s_w[q] = w;
    const float* kp = kp_sel + ((size_t)n * LL + q) * NK;
    for (int k = 0; k < NK; ++k)
        s_lp[k][q] = logf(fmaxf(kp[k], 1e-10f)) * w * 0.01f;
    __syncthreads();
    if (q == 0) {
        float wsum = 0.f;
        for (int t = 0; t < LL; ++t) wsum += s_w[t];
        float inv = 1.0f / (wsum + 1e-10f);
        float r = b_sel[0];
        for (int k = 0; k < NK; ++k) {
            float s = 0.f;
            for (int t = 0; t < LL; ++t) s += s_lp[k][t];
            r += s * inv * W_sel[k];
        }
        dsel[n] = r;
    }
}

// ---------------- K4: att logits -> softmax over q -> denoise ----------------
__global__ __launch_bounds__(256) void k_att_denoise(
    const float* __restrict__ kp_att, const float* __restrict__ mask_evidence,
    const float* __restrict__ W_att, const float* __restrict__ b_att,
    const float* __restrict__ hid, float* __restrict__ denoise)
{
    int idx = blockIdx.x;       // i*NN + n
    int n = idx % NN, i = idx / NN;
    __shared__ float att[LL];
    int tid = threadIdx.x;
    if (tid < LL) {
        int q = tid;
        const float* kp = kp_att + (((size_t)i * NN + n) * LL + q) * NK;
        float s = b_att[0];
        for (int k = 0; k < NK; ++k) s += logf(fmaxf(kp[k], 1e-10f)) * W_att[k];
        if (mask_evidence[n * LL + q] == 0.f) s = -10000.f;
        att[q] = s;
    }
    __syncthreads();
    if (tid == 0) {
        float m = -1e30f;
        for (int t = 0; t < LL; ++t) m = fmaxf(m, att[t]);
        float ssum = 0.f;
        for (int t = 0; t < LL; ++t) { float ev = __expf(att[t] - m); att[t] = ev; ssum += ev; }
        float inv = 1.0f / ssum;
        for (int t = 0; t < LL; ++t) att[t] *= inv;
    }
    __syncthreads();
    const float* hrow = hid + (size_t)n * LL * HH;
    for (int h = tid; h < HH; h += 256) {
        float a = 0.f;
        for (int q = 0; q < LL; ++q) a += att[q] * hrow[(size_t)q * HH + h];
        denoise[((size_t)i * NN + n) * HH + h] = a;
    }
}

// ---------------- K5: GAT scalar gate per (i, n) ----------------
__global__ __launch_bounds__(128) void k_gat(
    const float* __restrict__ inputs, const float* __restrict__ denoise,
    const float* __restrict__ W1, const float* __restrict__ b1,
    const float* __restrict__ W2, const float* __restrict__ b2,
    float* __restrict__ gsc)
{
    int idx = blockIdx.x;       // i*NN + n
    int n = idx % NN, i = idx / NN;
    int b = n / NE;
    int j = threadIdx.x;        // 0..127
    const float* xin = inputs + ((size_t)b * NE + i) * HH;
    const float* xde = denoise + (size_t)idx * HH;
    float a = b1[j];
    for (int t = 0; t < HH; ++t) a += xin[t] * W1[(size_t)t * 128 + j];
    for (int t = 0; t < HH; ++t) a += xde[t] * W1[(size_t)(HH + t) * 128 + j];
    a = fmaxf(a, 0.f);
    float v = a * W2[j];
    #pragma unroll
    for (int o = 32; o > 0; o >>= 1) v += __shfl_down(v, o, 64);
    __shared__ float red[2];
    if ((j & 63) == 0) red[j >> 6] = v;
    __syncthreads();
    if (j == 0) gsc[idx] = red[0] + red[1] + b2[0];
}

// ---------------- K6: final combine, softmaxes, output ----------------
__global__ __launch_bounds__(256) void k_final(
    const float* __restrict__ inputs, const float* __restrict__ denoise,
    const float* __restrict__ gsc, const float* __restrict__ dsel,
    const float* __restrict__ inf_W, const float* __restrict__ inf_b,
    float* __restrict__ out)
{
    int b = blockIdx.x;        // 0..15
    int tid = threadIdx.x;
    __shared__ float sp[NE];
    __shared__ float wde[NE][NE];   // [i][e]
    __shared__ float logi[NCLS];
    __shared__ float accp[NCLS];
    __shared__ float red[4];
    if (tid == 0) {
        float m = -1e30f;
        for (int e2 = 0; e2 < NE; ++e2) m = fmaxf(m, dsel[b * NE + e2]);
        float s = 0.f;
        for (int e2 = 0; e2 < NE; ++e2) { float v = __expf(dsel[b * NE + e2] - m); sp[e2] = v; s += v; }
        for (int e2 = 0; e2 < NE; ++e2) sp[e2] /= s;
        for (int i = 0; i < NE; ++i) {
            float mm = -1e30f;
            for (int e2 = 0; e2 < NE; ++e2) mm = fmaxf(mm, gsc[i * NN + b * NE + e2]);
            float ss = 0.f;
            for (int e2 = 0; e2 < NE; ++e2) { float v = __expf(gsc[i * NN + b * NE + e2] - mm); wde[i][e2] = v; ss += v; }
            for (int e2 = 0; e2 < NE; ++e2) wde[i][e2] /= ss;
        }
        for (int c = 0; c < NCLS; ++c) accp[c] = 0.f;
    }
    __syncthreads();
    for (int i = 0; i < NE; ++i) {
        float part[NCLS] = {0.f, 0.f, 0.f};
        for (int t = tid; t < 2 * HH; t += 256) {
            float f;
            if (t < HH) f = inputs[((size_t)b * NE + i) * HH + t];
            else {
                int h = t - HH;
                float a = 0.f;
                for (int e2 = 0; e2 < NE; ++e2)
                    a += wde[i][e2] * denoise[((size_t)i * NN + b * NE + e2) * HH + h];
                f = a;
            }
            #pragma unroll
            for (int c = 0; c < NCLS; ++c) part[c] += f * inf_W[(size_t)t * NCLS + c];
        }
        for (int c = 0; c < NCLS; ++c) {
            float v = part[c];
            #pragma unroll
            for (int o = 32; o > 0; o >>= 1) v += __shfl_down(v, o, 64);
            if ((tid & 63) == 0) red[tid >> 6] = v;
            __syncthreads();
            if (tid == 0) logi[c] = red[0] + red[1] + red[2] + red[3] + inf_b[c];
            __syncthreads();
        }
        if (tid == 0) {
            float mm = fmaxf(fmaxf(logi[0], logi[1]), logi[2]);
            float e0 = __expf(logi[0] - mm), e1 = __expf(logi[1] - mm), e2 = __expf(logi[2] - mm);
            float ss = e0 + e1 + e2;
            accp[0] += sp[i] * (e0 / ss);
            accp[1] += sp[i] * (e1 / ss);
            accp[2] += sp[i] * (e2 / ss);
        }
        __syncthreads();
    }
    if (tid < NCLS) out[b * NCLS + tid] = logf(accp[tid]);
}

extern "C" void kernel_launch(void* const* d_in, const int* in_sizes, int n_in,
                              void* d_out, int out_size, void* d_ws, size_t ws_size,
                              hipStream_t stream) {
    (void)in_sizes; (void)n_in; (void)out_size; (void)ws_size;
    const float* hid           = (const float*)d_in[0];
    const float* inputs        = (const float*)d_in[1];
    const float* mask_text     = (const float*)d_in[2];
    const float* mask_claim    = (const float*)d_in[3];
    const float* mask_evidence = (const float*)d_in[4];
    const float* W_att  = (const float*)d_in[5];
    const float* b_att  = (const float*)d_in[6];
    const float* W_sel  = (const float*)d_in[7];
    const float* b_sel  = (const float*)d_in[8];
    const float* gat_W1 = (const float*)d_in[9];
    const float* gat_b1 = (const float*)d_in[10];
    const float* gat_W2 = (const float*)d_in[11];
    const float* gat_b2 = (const float*)d_in[12];
    const float* inf_W  = (const float*)d_in[13];
    const float* inf_b  = (const float*)d_in[14];
    (void)gat_b1;

    float* ws = (float*)d_ws;
    float* invn   = ws;                         // 10240
    float* kp_att = invn + NN * LL;             // 1,075,200
    float* kp_sel = kp_att + (size_t)NE * NN * LL * NK;   // 215,040
    float* dsel   = kp_sel + (size_t)NN * LL * NK;        // 80
    float* denoi  = dsel + NN;                  // 307,200
    float* gsc    = denoi + (size_t)NE * NN * HH;         // 400

    k_invnorm<<<NN * LL, 256, 0, stream>>>(hid, invn);
    dim3 g2(2, 25, 16);
    k_simpool<<<g2, 256, 0, stream>>>(hid, invn, mask_text, mask_evidence, kp_att, kp_sel);
    k_sel<<<NN, 128, 0, stream>>>(kp_sel, mask_claim, W_sel, b_sel, dsel);
    k_att_denoise<<<NE * NN, 256, 0, stream>>>(kp_att, mask_evidence, W_att, b_att, hid, denoi);
    k_gat<<<NE * NN, 128, 0, stream>>>(inputs, denoi, gat_W1, gat_b1, gat_W2, gat_b2, gsc);
    k_final<<<NB, 256, 0, stream>>>(inputs, denoi, gsc, dsel, inf_W, inf_b, (float*)d_out);
}

// Round 2
// 232.095 us; speedup vs baseline: 1.6754x; 1.6754x over previous
//
#include <hip/hip_runtime.h>
#include <math.h>

#define NB 16
#define NE 5
#define LL 128
#define HH 768
#define NK 21
#define NCLS 3
#define NN (NB*NE)   // 80

typedef float f32x4 __attribute__((ext_vector_type(4)));
typedef short s16x8 __attribute__((ext_vector_type(8)));

__device__ __forceinline__ short bf16rne(float f) {
    union { float f; unsigned u; } c; c.f = f;
    unsigned u = c.u;
    unsigned r = (u + 0x7FFFu + ((u >> 16) & 1u)) >> 16;
    return (short)r;
}
__device__ __forceinline__ float bf16tof(short h) {
    union { unsigned u; float f; } c; c.u = ((unsigned)(unsigned short)h) << 16;
    return c.f;
}

// ---------------- K1: inverse L2 norms ----------------
__global__ __launch_bounds__(256) void k_invnorm(const float* __restrict__ hid,
                                                 float* __restrict__ invn) {
    int row = blockIdx.x;
    const float* x = hid + (size_t)row * HH;
    float ss = 0.f;
    for (int h = threadIdx.x; h < HH; h += 256) { float v = x[h]; ss += v * v; }
    __shared__ float red[4];
    int lane = threadIdx.x & 63, w = threadIdx.x >> 6;
    #pragma unroll
    for (int o = 32; o > 0; o >>= 1) ss += __shfl_down(ss, o, 64);
    if (lane == 0) red[w] = ss;
    __syncthreads();
    if (threadIdx.x == 0) {
        float t = red[0] + red[1] + red[2] + red[3];
        invn[row] = 1.0f / fmaxf(sqrtf(t), 1e-12f);
    }
}

// ---------------- K2: MFMA sim tile (bf16 hi/lo 3-pass) + kernel pooling ----
// grid: 400 blocks; b = bid&15 (XCD locality), pair = bid>>4.
// Block: 256 thr = 4 waves; wave w owns q rows [w*32, w*32+32), all 128 d cols.
__global__ __launch_bounds__(256, 2) void k_simpool(
    const float* __restrict__ hid, const float* __restrict__ invn,
    const float* __restrict__ mask_text, const float* __restrict__ mask_evidence,
    float* __restrict__ kp_att, float* __restrict__ kp_sel)
{
    const int n = blockIdx.x;
    const int b = n & 15, pair = n >> 4;
    const int e = pair / NE, ep = pair - e * NE;
    const int nq = b * NE + e, nd = b * NE + ep;
    const bool diag = (e == ep);
    const int tid = threadIdx.x;
    const int lane = tid & 63, w = tid >> 6;
    const int lx = tid & 15, lg = (tid & 63) >> 4;

    // frag-linear tiles: 16B unit u(row,kc) = (row>>4)*64 + kc*16 + (row&15)
    __shared__ short sAh[4096], sAl[4096], sBh[4096], sBl[4096];
    __shared__ float sIQ[LL], sID[LL], sMT[LL], sME[LL];

    if (tid < LL) {
        sIQ[tid] = invn[nq * LL + tid];
        sID[tid] = invn[nd * LL + tid];
        sMT[tid] = mask_text[nd * LL + tid];
        sME[tid] = mask_evidence[nd * LL + tid];
    }

    const int srow = tid & 127;
    const int isB = tid >> 7;
    const float* src = hid + ((size_t)(isB ? nd : nq) * LL + srow) * HH;
    short* dh = isB ? sBh : sAh;
    short* dl = isB ? sBl : sAl;
    const int ub = (srow >> 4) * 64 + (srow & 15);

    float4 x[8];
    #pragma unroll
    for (int i = 0; i < 8; ++i) x[i] = reinterpret_cast<const float4*>(src)[i];

    f32x4 acc[2][8];
    #pragma unroll
    for (int mi = 0; mi < 2; ++mi)
        #pragma unroll
        for (int nj = 0; nj < 8; ++nj) acc[mi][nj] = (f32x4){0.f, 0.f, 0.f, 0.f};

    for (int step = 0; step < HH / 32; ++step) {
        // convert fp32 -> bf16 hi/lo, write frag-linear LDS
        #pragma unroll
        for (int kc = 0; kc < 4; ++kc) {
            float f[8];
            f[0] = x[2*kc].x; f[1] = x[2*kc].y; f[2] = x[2*kc].z; f[3] = x[2*kc].w;
            f[4] = x[2*kc+1].x; f[5] = x[2*kc+1].y; f[6] = x[2*kc+1].z; f[7] = x[2*kc+1].w;
            s16x8 hv, lv;
            #pragma unroll
            for (int i2 = 0; i2 < 8; ++i2) {
                short h = bf16rne(f[i2]);
                hv[i2] = h;
                lv[i2] = bf16rne(f[i2] - bf16tof(h));
            }
            *reinterpret_cast<s16x8*>(&dh[(ub + kc * 16) * 8]) = hv;
            *reinterpret_cast<s16x8*>(&dl[(ub + kc * 16) * 8]) = lv;
        }
        __syncthreads();
        // prefetch next K-chunk (hides global latency under MFMA)
        if (step < HH / 32 - 1) {
            const float* s2 = src + (step + 1) * 32;
            #pragma unroll
            for (int i = 0; i < 8; ++i) x[i] = reinterpret_cast<const float4*>(s2)[i];
        }
        s16x8 ah[2], al[2];
        #pragma unroll
        for (int mi = 0; mi < 2; ++mi) {
            ah[mi] = *reinterpret_cast<const s16x8*>(&sAh[((w * 2 + mi) * 64 + lane) * 8]);
            al[mi] = *reinterpret_cast<const s16x8*>(&sAl[((w * 2 + mi) * 64 + lane) * 8]);
        }
        #pragma unroll
        for (int nj = 0; nj < 8; ++nj) {
            s16x8 bh = *reinterpret_cast<const s16x8*>(&sBh[(nj * 64 + lane) * 8]);
            s16x8 bl = *reinterpret_cast<const s16x8*>(&sBl[(nj * 64 + lane) * 8]);
            #pragma unroll
            for (int mi = 0; mi < 2; ++mi) {
                acc[mi][nj] = __builtin_amdgcn_mfma_f32_16x16x32_bf16(ah[mi], bh, acc[mi][nj], 0, 0, 0);
                acc[mi][nj] = __builtin_amdgcn_mfma_f32_16x16x32_bf16(ah[mi], bl, acc[mi][nj], 0, 0, 0);
                acc[mi][nj] = __builtin_amdgcn_mfma_f32_16x16x32_bf16(al[mi], bh, acc[mi][nj], 0, 0, 0);
            }
        }
        __syncthreads();
    }

    // epilogue: scale by invn (l2norm), kernel-pool, reduce, store
    float idv[8], mtv[8], mev[8];
    #pragma unroll
    for (int nj = 0; nj < 8; ++nj) {
        int col = nj * 16 + lx;
        idv[nj] = sID[col]; mtv[nj] = sMT[col]; mev[nj] = diag ? sME[col] : 0.f;
    }
    float iqv[2][4];
    #pragma unroll
    for (int mi = 0; mi < 2; ++mi)
        #pragma unroll
        for (int r = 0; r < 4; ++r)
            iqv[mi][r] = sIQ[w * 32 + mi * 16 + lg * 4 + r];

    #pragma unroll
    for (int mi = 0; mi < 2; ++mi)
        #pragma unroll
        for (int nj = 0; nj < 8; ++nj)
            #pragma unroll
            for (int r = 0; r < 4; ++r)
                acc[mi][nj][r] *= iqv[mi][r] * idv[nj];

    const size_t obase = ((size_t)ep * NN + nq) * LL;
    for (int k = 0; k < NK; ++k) {
        const float mu = (k == 0) ? 1.0f : (0.95f - 0.1f * (k - 1));
        const float nc2 = (k == 0) ? (-5.0e5f * 1.4426950408889634f)
                                   : (-50.0f * 1.4426950408889634f);
        float pa[2][4], ps[2][4];
        #pragma unroll
        for (int mi = 0; mi < 2; ++mi)
            #pragma unroll
            for (int r = 0; r < 4; ++r) { pa[mi][r] = 0.f; ps[mi][r] = 0.f; }
        #pragma unroll
        for (int mi = 0; mi < 2; ++mi)
            #pragma unroll
            for (int nj = 0; nj < 8; ++nj)
                #pragma unroll
                for (int r = 0; r < 4; ++r) {
                    float d = acc[mi][nj][r] - mu;
                    float gg = exp2f(d * d * nc2);
                    pa[mi][r] += mtv[nj] * gg;
                    ps[mi][r] += mev[nj] * gg;
                }
        #pragma unroll
        for (int o = 1; o < 16; o <<= 1)
            #pragma unroll
            for (int mi = 0; mi < 2; ++mi)
                #pragma unroll
                for (int r = 0; r < 4; ++r)
                    pa[mi][r] += __shfl_xor(pa[mi][r], o, 64);
        if (diag) {
            #pragma unroll
            for (int o = 1; o < 16; o <<= 1)
                #pragma unroll
                for (int mi = 0; mi < 2; ++mi)
                    #pragma unroll
                    for (int r = 0; r < 4; ++r)
                        ps[mi][r] += __shfl_xor(ps[mi][r], o, 64);
        }
        if (lx == 0) {
            #pragma unroll
            for (int mi = 0; mi < 2; ++mi)
                #pragma unroll
                for (int r = 0; r < 4; ++r) {
                    int row = w * 32 + mi * 16 + lg * 4 + r;
                    kp_att[(obase + row) * NK + k] = pa[mi][r];
                    if (diag) kp_sel[((size_t)nq * LL + row) * NK + k] = ps[mi][r];
                }
        }
    }
}

// ---------------- K3: sel logits per doc ----------------
__global__ __launch_bounds__(128) void k_sel(
    const float* __restrict__ kp_sel, const float* __restrict__ mask_claim,
    const float* __restrict__ W_sel, const float* __restrict__ b_sel,
    float* __restrict__ dsel)
{
    int n = blockIdx.x;
    int q = threadIdx.x;
    __shared__ float s_lp[NK][LL + 1];
    __shared__ float s_w[LL];
    float w = mask_claim[n * LL + q];
    s_w[q] = w;
    const float* kp = kp_sel + ((size_t)n * LL + q) * NK;
    for (int k = 0; k < NK; ++k)
        s_lp[k][q] = logf(fmaxf(kp[k], 1e-10f)) * w * 0.01f;
    __syncthreads();
    if (q == 0) {
        float wsum = 0.f;
        for (int t = 0; t < LL; ++t) wsum += s_w[t];
        float inv = 1.0f / (wsum + 1e-10f);
        float r = b_sel[0];
        for (int k = 0; k < NK; ++k) {
            float s = 0.f;
            for (int t = 0; t < LL; ++t) s += s_lp[k][t];
            r += s * inv * W_sel[k];
        }
        dsel[n] = r;
    }
}

// ---------------- K4: att logits -> wave-parallel softmax -> denoise --------
__global__ __launch_bounds__(256) void k_att_denoise(
    const float* __restrict__ kp_att, const float* __restrict__ mask_evidence,
    const float* __restrict__ W_att, const float* __restrict__ b_att,
    const float* __restrict__ hid, float* __restrict__ denoise)
{
    int idx = blockIdx.x;       // i*NN + n
    int n = idx % NN;
    __shared__ float att[LL];
    int tid = threadIdx.x;
    if (tid < LL) {
        int q = tid;
        const float* kp = kp_att + ((size_t)idx * LL + q) * NK;
        float s = b_att[0];
        for (int k = 0; k < NK; ++k) s += logf(fmaxf(kp[k], 1e-10f)) * W_att[k];
        if (mask_evidence[n * LL + q] == 0.f) s = -10000.f;
        att[q] = s;
    }
    __syncthreads();
    if (tid < 64) {
        float a0 = att[tid], a1 = att[tid + 64];
        float m = fmaxf(a0, a1);
        #pragma unroll
        for (int o = 32; o > 0; o >>= 1) m = fmaxf(m, __shfl_xor(m, o, 64));
        float e0 = __expf(a0 - m), e1 = __expf(a1 - m);
        float s = e0 + e1;
        #pragma unroll
        for (int o = 32; o > 0; o >>= 1) s += __shfl_xor(s, o, 64);
        float inv = 1.0f / s;
        att[tid] = e0 * inv; att[tid + 64] = e1 * inv;
    }
    __syncthreads();
    const float* hrow = hid + (size_t)n * LL * HH;
    for (int h = tid; h < HH; h += 256) {
        float a = 0.f;
        for (int q = 0; q < LL; ++q) a += att[q] * hrow[(size_t)q * HH + h];
        denoise[(size_t)idx * HH + h] = a;
    }
}

// ---------------- K5a: transpose W1 -> W1T[128][1536] ----------------
__global__ __launch_bounds__(256) void k_w1t(const float* __restrict__ W1,
                                             float* __restrict__ w1t) {
    int o = blockIdx.x * 256 + threadIdx.x;   // 196608 total
    int j = o / 1536, t = o - j * 1536;
    w1t[o] = W1[(size_t)t * 128 + j];
}

// ---------------- K5b: GAT gate — one wave per (j-pair, 8 p's) --------------
// part[p*64 + jp] = sum_j∈pair relu(feat·W1col_j + b1_j) * W2_j
__global__ __launch_bounds__(256) void k_gat2(
    const float* __restrict__ inputs, const float* __restrict__ denoise,
    const float* __restrict__ w1t, const float* __restrict__ b1,
    const float* __restrict__ W2, float* __restrict__ part)
{
    int wid = blockIdx.x * 4 + (threadIdx.x >> 6);   // 0..3199
    int l = threadIdx.x & 63;
    int jp = wid & 63;
    int po = wid >> 6;                                // 0..49
    int j0 = jp * 2, j1 = j0 + 1;
    int pb = po * 8;

    float a0[8], a1[8];
    #pragma unroll
    for (int u = 0; u < 8; ++u) { a0[u] = 0.f; a1[u] = 0.f; }
    const float* wc0 = w1t + (size_t)j0 * 1536;
    const float* wc1 = w1t + (size_t)j1 * 1536;
    const float* fin[8]; const float* fde[8];
    #pragma unroll
    for (int u = 0; u < 8; ++u) {
        int p = pb + u;
        int i = p / NN; int n2 = p - i * NN; int bb = n2 / NE;
        fin[u] = inputs + ((size_t)bb * NE + i) * HH;
        fde[u] = denoise + (size_t)p * HH;
    }
    for (int it = 0; it < 24; ++it) {
        int t = it * 64 + l;
        float wv0 = wc0[t], wv1 = wc1[t];
        const bool isde = (it >= 12);
        int t2 = isde ? (t - HH) : t;
        #pragma unroll
        for (int u = 0; u < 8; ++u) {
            float fv = isde ? fde[u][t2] : fin[u][t2];
            a0[u] += fv * wv0;
            a1[u] += fv * wv1;
        }
    }
    #pragma unroll
    for (int u = 0; u < 8; ++u) {
        #pragma unroll
        for (int o = 32; o > 0; o >>= 1) {
            a0[u] += __shfl_xor(a0[u], o, 64);
            a1[u] += __shfl_xor(a1[u], o, 64);
        }
    }
    float bb0 = b1[j0], bb1 = b1[j1], w20 = W2[j0], w21 = W2[j1];
    if (l == 0) {
        #pragma unroll
        for (int u = 0; u < 8; ++u) {
            float v = fmaxf(a0[u] + bb0, 0.f) * w20 + fmaxf(a1[u] + bb1, 0.f) * w21;
            part[(size_t)(pb + u) * 64 + jp] = v;
        }
    }
}

// ---------------- K5c: deterministic reduce of part -> gsc ----------------
__global__ __launch_bounds__(256) void k_gatred(const float* __restrict__ part,
                                                float* __restrict__ gsc) {
    int p = blockIdx.x * 256 + threadIdx.x;
    if (p < NE * NN) {
        float s = 0.f;
        for (int jp = 0; jp < 64; ++jp) s += part[(size_t)p * 64 + jp];
        gsc[p] = s;   // b2 omitted: uniform shift, softmax-invariant
    }
}

// ---------------- K6: final combine, softmaxes, output ----------------
__global__ __launch_bounds__(256) void k_final(
    const float* __restrict__ inputs, const float* __restrict__ denoise,
    const float* __restrict__ gsc, const float* __restrict__ dsel,
    const float* __restrict__ inf_W, const float* __restrict__ inf_b,
    float* __restrict__ out)
{
    int b = blockIdx.x;
    int tid = threadIdx.x;
    __shared__ float sp[NE];
    __shared__ float wde[NE][NE];
    __shared__ float logi[NCLS];
    __shared__ float accp[NCLS];
    __shared__ float red[4];
    if (tid == 0) {
        float m = -1e30f;
        for (int e2 = 0; e2 < NE; ++e2) m = fmaxf(m, dsel[b * NE + e2]);
        float s = 0.f;
        for (int e2 = 0; e2 < NE; ++e2) { float v = __expf(dsel[b * NE + e2] - m); sp[e2] = v; s += v; }
        for (int e2 = 0; e2 < NE; ++e2) sp[e2] /= s;
        for (int i = 0; i < NE; ++i) {
            float mm = -1e30f;
            for (int e2 = 0; e2 < NE; ++e2) mm = fmaxf(mm, gsc[i * NN + b * NE + e2]);
            float ss = 0.f;
            for (int e2 = 0; e2 < NE; ++e2) { float v = __expf(gsc[i * NN + b * NE + e2] - mm); wde[i][e2] = v; ss += v; }
            for (int e2 = 0; e2 < NE; ++e2) wde[i][e2] /= ss;
        }
        for (int c = 0; c < NCLS; ++c) accp[c] = 0.f;
    }
    __syncthreads();
    for (int i = 0; i < NE; ++i) {
        float part[NCLS] = {0.f, 0.f, 0.f};
        for (int t = tid; t < 2 * HH; t += 256) {
            float f;
            if (t < HH) f = inputs[((size_t)b * NE + i) * HH + t];
            else {
                int h = t - HH;
                float a = 0.f;
                for (int e2 = 0; e2 < NE; ++e2)
                    a += wde[i][e2] * denoise[((size_t)i * NN + b * NE + e2) * HH + h];
                f = a;
            }
            #pragma unroll
            for (int c = 0; c < NCLS; ++c) part[c] += f * inf_W[(size_t)t * NCLS + c];
        }
        for (int c = 0; c < NCLS; ++c) {
            float v = part[c];
            #pragma unroll
            for (int o = 32; o > 0; o >>= 1) v += __shfl_down(v, o, 64);
            if ((tid & 63) == 0) red[tid >> 6] = v;
            __syncthreads();
            if (tid == 0) logi[c] = red[0] + red[1] + red[2] + red[3] + inf_b[c];
            __syncthreads();
        }
        if (tid == 0) {
            float mm = fmaxf(fmaxf(logi[0], logi[1]), logi[2]);
            float e0 = __expf(logi[0] - mm), e1 = __expf(logi[1] - mm), e2 = __expf(logi[2] - mm);
            float ss = e0 + e1 + e2;
            accp[0] += sp[i] * (e0 / ss);
            accp[1] += sp[i] * (e1 / ss);
            accp[2] += sp[i] * (e2 / ss);
        }
        __syncthreads();
    }
    if (tid < NCLS) out[b * NCLS + tid] = logf(accp[tid]);
}

extern "C" void kernel_launch(void* const* d_in, const int* in_sizes, int n_in,
                              void* d_out, int out_size, void* d_ws, size_t ws_size,
                              hipStream_t stream) {
    (void)in_sizes; (void)n_in; (void)out_size; (void)ws_size;
    const float* hid           = (const float*)d_in[0];
    const float* inputs        = (const float*)d_in[1];
    const float* mask_text     = (const float*)d_in[2];
    const float* mask_claim    = (const float*)d_in[3];
    const float* mask_evidence = (const float*)d_in[4];
    const float* W_att  = (const float*)d_in[5];
    const float* b_att  = (const float*)d_in[6];
    const float* W_sel  = (const float*)d_in[7];
    const float* b_sel  = (const float*)d_in[8];
    const float* gat_W1 = (const float*)d_in[9];
    const float* gat_b1 = (const float*)d_in[10];
    const float* gat_W2 = (const float*)d_in[11];
    const float* gat_b2 = (const float*)d_in[12];
    const float* inf_W  = (const float*)d_in[13];
    const float* inf_b  = (const float*)d_in[14];
    (void)gat_b2;

    float* ws = (float*)d_ws;
    float* invn   = ws;                                    // 10,240
    float* kp_att = invn + NN * LL;                        // 1,075,200
    float* kp_sel = kp_att + (size_t)NE * NN * LL * NK;    // 215,040
    float* dsel   = kp_sel + (size_t)NN * LL * NK;         // 80
    float* denoi  = dsel + NN;                             // 307,200
    float* gsc    = denoi + (size_t)NE * NN * HH;          // 400
    float* w1t    = gsc + NE * NN;                         // 196,608
    float* part   = w1t + 2 * HH * 128;                    // 25,600

    k_invnorm<<<NN * LL, 256, 0, stream>>>(hid, invn);
    k_w1t<<<(2 * HH * 128) / 256, 256, 0, stream>>>(gat_W1, w1t);
    k_simpool<<<NB * 25, 256, 0, stream>>>(hid, invn, mask_text, mask_evidence, kp_att, kp_sel);
    k_sel<<<NN, 128, 0, stream>>>(kp_sel, mask_claim, W_sel, b_sel, dsel);
    k_att_denoise<<<NE * NN, 256, 0, stream>>>(kp_att, mask_evidence, W_att, b_att, hid, denoi);
    k_gat2<<<800, 256, 0, stream>>>(inputs, denoi, w1t, gat_b1, gat_W2, part);
    k_gatred<<<2, 256, 0, stream>>>(part, gsc);
    k_final<<<NB, 256, 0, stream>>>(inputs, denoi, gsc, dsel, inf_W, inf_b, (float*)d_out);
}